// Round 7
// baseline (7088.792 us; speedup 1.0000x reference)
//
#include <hip/hip_runtime.h>
#include <math.h>

#define BB 64
#define SS 512
#define DD 207
#define HH 256
#define LDW 676   // gate-weight LDS row stride (%32==4 -> staggered banks)
#define ROW 260   // readout-weight LDS row stride
#define AG __HIP_MEMORY_SCOPE_AGENT

// ============ v7: single-XCD recurrence, discovered placement ============
// 256 blocks x 512 threads; blocks register XCC_ID (device-scope atomics);
// first XCD collecting 32 blocks is chosen; its rank-0..31 blocks become the
// workers, everyone else exits. Worker r owns hidden units [8r,8r+8) (24 gate
// rows) + readout rows [d0,d1). Step-slot rotation buffer (virgin lines):
//   slot t rows 0..413: xin_t ; 414..415 pad ; 416..671: h_t
// FAST path (self-test verified same-XCD): plain payload stores -> shared L2;
// readers' virgin-line misses hit the dirty L2 line (~150cy, no L3 trip).
// BAIL path: sc1 payload stores (round-6 semantics, any placement). Flags sc1.
#define SROWS 672
#define HOFF  416
#define SLOT  (SROWS * 64)
#define BUF_FLOATS ((size_t)SS * SLOT)
#define FLAG_U32 (64 * 32)
#define STAGE_FLOATS ((size_t)SS * DD * 64)
#define WS_NEED7 ((BUF_FLOATS + FLAG_U32 + STAGE_FLOATS) * sizeof(float))
#define NW 32
#define BS7 512
#define GRID7 256
#define HWREG_XCC (20 | (31 << 11))   // HW_REG_XCC_ID, offset 0, size 32
#define MAGICF 1.0e30f

// registration block lives in slot 511's xin rows (never touched by the loop:
// step SS-1 breaks before publishing xin). Layout (u32 idx from R0):
//   [0..255]   per-XCD counters, stride 32
//   [256] total  [257] chosen(int)  [258] bail
//   [512..1535] xcc probes, stride 32
//   floats R0+2048.. : magic lines, stride 32 (left poisoned by init = virgin)
#define R0 ((size_t)(SS - 1) * SLOT)

// ---- v3 fallback layout ----
#define V3_AROWS 928
#define V3_HBASE 416
#define V3_ACT (V3_AROWS * 64)
#define V3_FLAGS (64 * 32)
#define V3_WS_SMALL ((size_t)(V3_ACT + V3_FLAGS) * sizeof(float))
#define V3_WS_FULL  ((size_t)(V3_ACT + V3_FLAGS + STAGE_FLOATS) * sizeof(float))
#define NWG 64

__device__ __forceinline__ void ast4(float* p, float v) {
    union { float f; unsigned u; } c; c.f = v;
    __hip_atomic_store((unsigned*)p, c.u, __ATOMIC_RELAXED, AG);
}

__global__ __launch_bounds__(256) void rnn_init7(float* __restrict__ ws) {
    int i = blockIdx.x * blockDim.x + threadIdx.x;
    for (int idx = i; idx < HH * 64; idx += gridDim.x * blockDim.x)
        ws[HOFF * 64 + idx] = 0.f;                    // h_0 = 0 (slot 0)
    unsigned* fl = (unsigned*)(ws + BUF_FLOATS);
    for (int idx = i; idx < FLAG_U32; idx += gridDim.x * blockDim.x)
        fl[idx] = 0u;
    unsigned* rc = (unsigned*)(ws + R0);
    for (int idx = i; idx < 2048; idx += gridDim.x * blockDim.x)
        rc[idx] = 0u;
    if (i == 0) ((int*)rc)[257] = -1;                 // chosen = -1
    // magic region (R0+2048..) left poisoned on purpose (virgin lines)
}

__global__ __launch_bounds__(BS7) void rnn_persist7(
    const float* __restrict__ x, const float* __restrict__ mask,
    const float* __restrict__ W_ih, const float* __restrict__ W_hh,
    const float* __restrict__ b_ih, const float* __restrict__ b_hh,
    const float* __restrict__ W_ro, const float* __restrict__ b_ro,
    float* __restrict__ ws, float* __restrict__ out)
{
    const int tid = threadIdx.x;
    float* buf = ws;
    unsigned* flags = (unsigned*)(ws + BUF_FLOATS);
    float* stage = ws + BUF_FLOATS + FLAG_U32;
    unsigned* rc   = (unsigned*)(ws + R0);
    unsigned* rpro = rc + 512;
    float*    rmag = ws + R0 + 2048;

    __shared__ int sh_rank, sh_xcc, sh_fast;

    // ---- registration ----
    if (tid == 0) {
        unsigned xcc = (unsigned)__builtin_amdgcn_s_getreg(HWREG_XCC);
        unsigned xb = xcc & 7;
        unsigned rank = __hip_atomic_fetch_add(&rc[xb * 32], 1u, __ATOMIC_RELAXED, AG);
        unsigned tot  = __hip_atomic_fetch_add(&rc[256], 1u, __ATOMIC_RELAXED, AG);
        int* chosen = (int*)&rc[257];
        if (rank == NW - 1) {
            int exp = -1;
            __hip_atomic_compare_exchange_strong(chosen, &exp, (int)xb,
                __ATOMIC_RELAXED, __ATOMIC_RELAXED, AG);
        }
        if (tot == GRID7 - 1) {     // everyone registered: pick max-count XCD
            unsigned best = 0; int bi = 0;
            for (int q = 0; q < 8; ++q) {
                unsigned c = __hip_atomic_load(&rc[q * 32], __ATOMIC_RELAXED, AG);
                if (c > best) { best = c; bi = q; }
            }
            int exp = -1;
            __hip_atomic_compare_exchange_strong(chosen, &exp, bi,
                __ATOMIC_RELAXED, __ATOMIC_RELAXED, AG);
        }
        int c;
        do { c = __hip_atomic_load(chosen, __ATOMIC_RELAXED, AG); } while (c == -1);
        sh_rank = (c == (int)xb && rank < NW) ? (int)rank : -1;
        sh_xcc = (int)xcc;
        sh_fast = 0;
    }
    __syncthreads();
    const int rank = sh_rank;
    if (rank < 0) return;
    const int myxcc = sh_xcc;

    unsigned gen = 0;

    // ---- L2-coherence self-test: do plain stores propagate to all workers? --
    if (tid == 0) {
        rmag[rank * 32] = MAGICF;  // plain store: stays dirty in this XCD's L2
        __hip_atomic_store(&rpro[rank * 32], (unsigned)myxcc, __ATOMIC_RELAXED, AG);
    }
    ++gen;
    asm volatile("s_waitcnt vmcnt(0)" ::: "memory");
    __syncthreads();
    if (tid == 0) __hip_atomic_store(&flags[rank * 32], gen, __ATOMIC_RELAXED, AG);
    if (tid < NW) {
        unsigned* f = &flags[tid * 32];
        while (__hip_atomic_load(f, __ATOMIC_RELAXED, AG) < gen) {}
    }
    __syncthreads();
    if (tid < NW) {
        float mg = rmag[tid * 32];     // virgin normal load: L2-hit iff same XCD
        unsigned pb = __hip_atomic_load(&rpro[tid * 32], __ATOMIC_RELAXED, AG);
        if (mg != MAGICF || pb != (unsigned)myxcc)
            __hip_atomic_fetch_or(&rc[258], 1u, __ATOMIC_RELAXED, AG);
    }
    ++gen;
    asm volatile("s_waitcnt vmcnt(0)" ::: "memory");
    __syncthreads();
    if (tid == 0) __hip_atomic_store(&flags[rank * 32], gen, __ATOMIC_RELAXED, AG);
    if (tid < NW) {
        unsigned* f = &flags[tid * 32];
        while (__hip_atomic_load(f, __ATOMIC_RELAXED, AG) < gen) {}
    }
    __syncthreads();
    if (tid == 0)
        sh_fast = (__hip_atomic_load(&rc[258], __ATOMIC_RELAXED, AG) == 0) ? 1 : 0;
    __syncthreads();
    const bool fast = (sh_fast != 0);

    // ---- LDS weight residency (24 gate rows + <=7 readout rows) ----
    __shared__ float wgl[24 * LDW];
    __shared__ float wrol[8 * ROW];
    __shared__ float red[8 * 24 * 64];   // per-wave gate partials (r,z merged; n=gi only)
    __shared__ float red2[8 * 8 * 64];   // per-wave gh_n partials (kept separate for r*gh_n)
    __shared__ float redB[8 * 8 * 64];   // readout partials
    __shared__ float hloc[8 * 64];
    __shared__ float bihl[24], bhhl[24], brol[8];

    const int d0 = (207 * rank) / NW;
    const int d1 = (207 * (rank + 1)) / NW;
    const int dc = d1 - d0;

    for (int i = tid; i < 24 * LDW; i += BS7) {
        int r = i / LDW, c = i - r * LDW;
        int rg = (r >> 3) * 256 + rank * 8 + (r & 7);   // g = r>>3, unit = r&7
        float v = 0.f;
        if (c < 414) v = W_ih[rg * 414 + c];
        else if (c >= 416 && c < 672) v = W_hh[rg * 256 + (c - 416)];
        wgl[i] = v;
    }
    for (int i = tid; i < 8 * 256; i += BS7) {
        int dl_ = i >> 8, j = i & 255;
        wrol[dl_ * ROW + j] = (dl_ < dc) ? W_ro[(d0 + dl_) * 256 + j] : 0.f;
    }
    if (tid < 24) {
        int rg = (tid >> 3) * 256 + rank * 8 + (tid & 7);
        bihl[tid] = b_ih[rg];
        bhhl[tid] = b_hh[rg];
    }
    if (tid < 8) brol[tid] = (tid < dc) ? b_ro[d0 + tid] : 0.f;
    hloc[tid] = 0.f;
    __syncthreads();

    const float4* A4 = (const float4*)buf;
    const int lane = tid & 63;
    const int wv = tid >> 6;   // 0..7
    const int u  = lane >> 4;  // 0..3; lane u handles local rows u+4j
    const int bp = lane & 15;

    const bool have = (tid < dc * 64);
    const int dl = tid >> 6, b = tid & 63;
    const size_t gbase = (size_t)b * (SS * DD) + (d0 + dl);
    float xv_pf = 0.f, mv_pf = 0.f;
    if (have) { xv_pf = x[gbase]; mv_pf = mask[gbase]; }

    for (int t = 0; t < SS; ++t) {
        const int sbase = t * SROWS;

        // ---- Phase B: readout partials from h_t (virgin cached reads) ----
        {
            float4 r0 = make_float4(0.f,0.f,0.f,0.f), r1 = r0;
            const int kb = wv * 32;
            #pragma unroll 2
            for (int k = 0; k < 32; k += 4) {
                float4 a0 = A4[(sbase + HOFF + kb + k + 0) * 16 + bp];
                float4 a1 = A4[(sbase + HOFF + kb + k + 1) * 16 + bp];
                float4 a2 = A4[(sbase + HOFF + kb + k + 2) * 16 + bp];
                float4 a3 = A4[(sbase + HOFF + kb + k + 3) * 16 + bp];
                float4 w0 = *(const float4*)&wrol[u * ROW + kb + k];
                float4 w1 = *(const float4*)&wrol[(u + 4) * ROW + kb + k];
                r0.x += a0.x*w0.x + a1.x*w0.y + a2.x*w0.z + a3.x*w0.w;
                r0.y += a0.y*w0.x + a1.y*w0.y + a2.y*w0.z + a3.y*w0.w;
                r0.z += a0.z*w0.x + a1.z*w0.y + a2.z*w0.z + a3.z*w0.w;
                r0.w += a0.w*w0.x + a1.w*w0.y + a2.w*w0.z + a3.w*w0.w;
                r1.x += a0.x*w1.x + a1.x*w1.y + a2.x*w1.z + a3.x*w1.w;
                r1.y += a0.y*w1.x + a1.y*w1.y + a2.y*w1.z + a3.y*w1.w;
                r1.z += a0.z*w1.x + a1.z*w1.y + a2.z*w1.z + a3.z*w1.w;
                r1.w += a0.w*w1.x + a1.w*w1.y + a2.w*w1.z + a3.w*w1.w;
            }
            float4* RB = (float4*)redB;
            RB[(wv * 8 + u) * 16 + bp] = r0;
            RB[(wv * 8 + u + 4) * 16 + bp] = r1;
        }
        __syncthreads();
        if (have) {
            float xh = brol[dl];
            #pragma unroll
            for (int w8 = 0; w8 < 8; ++w8) xh += redB[(w8 * 8 + dl) * 64 + b];
            stage[((size_t)t * DD + d0 + dl) * 64 + b] = xh;   // coalesced
            if (t < SS - 1) {
                float xi = (mv_pf > 0.5f) ? xv_pf : xh;
                float* p0 = &buf[(size_t)(sbase + d0 + dl) * 64 + b];
                float* p1 = &buf[(size_t)(sbase + 207 + d0 + dl) * 64 + b];
                if (fast) { *p0 = xi; *p1 = mv_pf; }
                else      { ast4(p0, xi); ast4(p1, mv_pf); }
            }
        }
        if (t == SS - 1) break;

        // ---- arrive 1: xin_t published ----
        ++gen;
        asm volatile("s_waitcnt vmcnt(0)" ::: "memory");
        __syncthreads();
        if (tid == 0) __hip_atomic_store(&flags[rank * 32], gen, __ATOMIC_RELAXED, AG);

        // ---- overlap poll window: gh partials (h rows are L2/L1-hot) ----
        // acc[0..3] = r,z rows (gi+gh merged); accN = gh_n (separate: n-gate
        // needs r * gh_n). acc[4..5] will take gi_n from the xin pass.
        float4 acc[6];
        #pragma unroll
        for (int j = 0; j < 6; ++j) acc[j] = make_float4(0.f,0.f,0.f,0.f);
        float4 accN0 = make_float4(0.f,0.f,0.f,0.f), accN1 = accN0;
        {
            const int wc0 = 416 + wv * 32, gr0 = sbase + HOFF + wv * 32;
            #pragma unroll 2
            for (int k = 0; k < 32; k += 4) {
                float4 a0 = A4[(gr0 + k + 0) * 16 + bp];
                float4 a1 = A4[(gr0 + k + 1) * 16 + bp];
                float4 a2 = A4[(gr0 + k + 2) * 16 + bp];
                float4 a3 = A4[(gr0 + k + 3) * 16 + bp];
                #pragma unroll
                for (int j = 0; j < 4; ++j) {        // rows u+4j : r,z gates
                    float4 w = *(const float4*)&wgl[(u + 4 * j) * LDW + wc0 + k];
                    acc[j].x += a0.x*w.x + a1.x*w.y + a2.x*w.z + a3.x*w.w;
                    acc[j].y += a0.y*w.x + a1.y*w.y + a2.y*w.z + a3.y*w.w;
                    acc[j].z += a0.z*w.x + a1.z*w.y + a2.z*w.z + a3.z*w.w;
                    acc[j].w += a0.w*w.x + a1.w*w.y + a2.w*w.z + a3.w*w.w;
                }
                float4 wn0 = *(const float4*)&wgl[(16 + u) * LDW + wc0 + k];
                float4 wn1 = *(const float4*)&wgl[(20 + u) * LDW + wc0 + k];
                accN0.x += a0.x*wn0.x + a1.x*wn0.y + a2.x*wn0.z + a3.x*wn0.w;
                accN0.y += a0.y*wn0.x + a1.y*wn0.y + a2.y*wn0.z + a3.y*wn0.w;
                accN0.z += a0.z*wn0.x + a1.z*wn0.y + a2.z*wn0.z + a3.z*wn0.w;
                accN0.w += a0.w*wn0.x + a1.w*wn0.y + a2.w*wn0.z + a3.w*wn0.w;
                accN1.x += a0.x*wn1.x + a1.x*wn1.y + a2.x*wn1.z + a3.x*wn1.w;
                accN1.y += a0.y*wn1.x + a1.y*wn1.y + a2.y*wn1.z + a3.y*wn1.w;
                accN1.z += a0.z*wn1.x + a1.z*wn1.y + a2.z*wn1.z + a3.z*wn1.w;
                accN1.w += a0.w*wn1.x + a1.w*wn1.y + a2.w*wn1.z + a3.w*wn1.w;
            }
        }
        {
            float4* R2 = (float4*)red2;
            R2[(wv * 8 + u) * 16 + bp] = accN0;
            R2[(wv * 8 + u + 4) * 16 + bp] = accN1;
        }

        // ---- wait 1 ----
        if (tid < NW) {
            unsigned* f = &flags[tid * 32];
            while (__hip_atomic_load(f, __ATOMIC_RELAXED, AG) < gen) {}
        }
        __syncthreads();

        // ---- xin GEMV: all 24 rows over this wave's 52-row slice ----
        {
            const int wc0 = wv * 52, gr0 = sbase + wv * 52;
            #pragma unroll 2
            for (int k = 0; k < 52; k += 4) {
                float4 a0 = A4[(gr0 + k + 0) * 16 + bp];
                float4 a1 = A4[(gr0 + k + 1) * 16 + bp];
                float4 a2 = A4[(gr0 + k + 2) * 16 + bp];
                float4 a3 = A4[(gr0 + k + 3) * 16 + bp];
                #pragma unroll
                for (int j = 0; j < 6; ++j) {
                    float4 w = *(const float4*)&wgl[(u + 4 * j) * LDW + wc0 + k];
                    acc[j].x += a0.x*w.x + a1.x*w.y + a2.x*w.z + a3.x*w.w;
                    acc[j].y += a0.y*w.x + a1.y*w.y + a2.y*w.z + a3.y*w.w;
                    acc[j].z += a0.z*w.x + a1.z*w.y + a2.z*w.z + a3.z*w.w;
                    acc[j].w += a0.w*w.x + a1.w*w.y + a2.w*w.z + a3.w*w.w;
                }
            }
            float4* R4 = (float4*)red;
            #pragma unroll
            for (int j = 0; j < 6; ++j)
                R4[(wv * 24 + u + 4 * j) * 16 + bp] = acc[j];
        }
        __syncthreads();

        // ---- epilogue: tid = uu*64 + b2 ----
        {
            const int uu = tid >> 6, b2 = tid & 63;
            float sr = 0.f, sz = 0.f, sni = 0.f, snh = 0.f;
            #pragma unroll
            for (int w8 = 0; w8 < 8; ++w8) {
                sr  += red[(w8 * 24 + 0 + uu) * 64 + b2];    // gi_r+gh_r
                sz  += red[(w8 * 24 + 8 + uu) * 64 + b2];    // gi_z+gh_z
                sni += red[(w8 * 24 + 16 + uu) * 64 + b2];   // gi_n
                snh += red2[(w8 * 8 + uu) * 64 + b2];        // gh_n
            }
            float r = 1.f / (1.f + __expf(-(sr + bihl[0 + uu] + bhhl[0 + uu])));
            float z = 1.f / (1.f + __expf(-(sz + bihl[8 + uu] + bhhl[8 + uu])));
            float n = tanhf(sni + bihl[16 + uu] + r * (snh + bhhl[16 + uu]));
            float hn = (1.f - z) * n + z * hloc[tid];
            hloc[tid] = hn;
            float* hp = &buf[(size_t)((t + 1) * SROWS + HOFF + rank * 8 + uu) * 64 + b2];
            if (fast) *hp = hn; else ast4(hp, hn);
        }

        // ---- arrive 2: h_{t+1} published ----
        ++gen;
        asm volatile("s_waitcnt vmcnt(0)" ::: "memory");
        __syncthreads();
        if (tid == 0) __hip_atomic_store(&flags[rank * 32], gen, __ATOMIC_RELAXED, AG);

        // ---- overlap: next x/mask prefetch ----
        if (have && t + 1 < SS - 1) {
            xv_pf = x[gbase + (size_t)(t + 1) * DD];
            mv_pf = mask[gbase + (size_t)(t + 1) * DD];
        }

        // ---- wait 2 ----
        if (tid < NW) {
            unsigned* f = &flags[tid * 32];
            while (__hip_atomic_load(f, __ATOMIC_RELAXED, AG) < gen) {}
        }
        __syncthreads();
    }
}

// epilogue: stage[t][d][b] -> out[b][t][d]
__global__ __launch_bounds__(256) void out_transpose(
    const float* __restrict__ stage, float* __restrict__ out)
{
    __shared__ float lds[DD * 65];
    const int t = blockIdx.x;
    const float* st = stage + (size_t)t * DD * 64;
    for (int i = threadIdx.x; i < DD * 64; i += 256) {
        int d = i >> 6, b = i & 63;
        lds[d * 65 + b] = st[i];
    }
    __syncthreads();
    for (int i = threadIdx.x; i < DD * 64; i += 256) {
        int b = i / DD, d = i - b * DD;
        out[(size_t)b * (SS * DD) + (size_t)t * DD + d] = lds[d * 65 + b];
    }
}

// ================= v3 fallback (round-3 proven) =================
__device__ __forceinline__ void run_range6(
    const float4* __restrict__ A4, const float* __restrict__ wgl,
    float* __restrict__ red, int u, int bp, int wc0, int gr0, int len, int slot)
{
    float4 c0 = make_float4(0.f, 0.f, 0.f, 0.f);
    float4 c1 = c0, c2 = c0;
    #pragma unroll 4
    for (int k = 0; k < len; k += 4) {
        float4 a0 = A4[(gr0 + k + 0) * 16 + bp];
        float4 a1 = A4[(gr0 + k + 1) * 16 + bp];
        float4 a2 = A4[(gr0 + k + 2) * 16 + bp];
        float4 a3 = A4[(gr0 + k + 3) * 16 + bp];
        float4 w0 = *(const float4*)&wgl[(0 + u) * LDW + wc0 + k];
        float4 w1 = *(const float4*)&wgl[(4 + u) * LDW + wc0 + k];
        float4 w2 = *(const float4*)&wgl[(8 + u) * LDW + wc0 + k];
        c0.x += a0.x*w0.x + a1.x*w0.y + a2.x*w0.z + a3.x*w0.w;
        c0.y += a0.y*w0.x + a1.y*w0.y + a2.y*w0.z + a3.y*w0.w;
        c0.z += a0.z*w0.x + a1.z*w0.y + a2.z*w0.z + a3.z*w0.w;
        c0.w += a0.w*w0.x + a1.w*w0.y + a2.w*w0.z + a3.w*w0.w;
        c1.x += a0.x*w1.x + a1.x*w1.y + a2.x*w1.z + a3.x*w1.w;
        c1.y += a0.y*w1.x + a1.y*w1.y + a2.y*w1.z + a3.y*w1.w;
        c1.z += a0.z*w1.x + a1.z*w1.y + a2.z*w1.z + a3.z*w1.w;
        c1.w += a0.w*w1.x + a1.w*w1.y + a2.w*w1.z + a3.w*w1.w;
        c2.x += a0.x*w2.x + a1.x*w2.y + a2.x*w2.z + a3.x*w2.w;
        c2.y += a0.y*w2.x + a1.y*w2.y + a2.y*w2.z + a3.y*w2.w;
        c2.z += a0.z*w2.x + a1.z*w2.y + a2.z*w2.z + a3.z*w2.w;
        c2.w += a0.w*w2.x + a1.w*w2.y + a2.w*w2.z + a3.w*w2.w;
    }
    float4* R4 = (float4*)red;
    R4[(slot * 12 + 0 + u) * 16 + bp] = c0;
    R4[(slot * 12 + 4 + u) * 16 + bp] = c1;
    R4[(slot * 12 + 8 + u) * 16 + bp] = c2;
}

__device__ __forceinline__ void v3_gbar(unsigned* flags, int wg, unsigned g) {
    __syncthreads();
    if (threadIdx.x < 64) {
        if (threadIdx.x == 0) {
            __builtin_amdgcn_fence(__ATOMIC_RELEASE, "agent");
            __hip_atomic_store(&flags[wg * 32], g, __ATOMIC_RELAXED, AG);
        }
        unsigned* f = &flags[threadIdx.x * 32];
        while (__hip_atomic_load(f, __ATOMIC_RELAXED, AG) < g) { }
        __builtin_amdgcn_fence(__ATOMIC_ACQUIRE, "agent");
    }
    __syncthreads();
}

__global__ __launch_bounds__(256) void v3_init(float* __restrict__ ws) {
    int i = blockIdx.x * blockDim.x + threadIdx.x;
    const int nz = (672 - 414) * 64;
    for (int idx = i; idx < nz; idx += gridDim.x * blockDim.x)
        ws[414 * 64 + idx] = 0.f;
    for (int idx = i; idx < V3_FLAGS; idx += gridDim.x * blockDim.x)
        ((unsigned*)(ws + V3_ACT))[idx] = 0u;
}

template<bool STAGE>
__global__ __launch_bounds__(256) void v3_persist(
    const float* __restrict__ x, const float* __restrict__ mask,
    const float* __restrict__ W_ih, const float* __restrict__ W_hh,
    const float* __restrict__ b_ih, const float* __restrict__ b_hh,
    const float* __restrict__ W_ro, const float* __restrict__ b_ro,
    float* __restrict__ ws, float* __restrict__ out)
{
    const int wg = blockIdx.x;
    const int tid = threadIdx.x;
    const int lane = tid & 63;
    const int wv = tid >> 6;
    float* actg = ws;
    unsigned* flags = (unsigned*)(ws + V3_ACT);
    float* stage = ws + V3_ACT + V3_FLAGS;
    __shared__ float wgl[12 * LDW];
    __shared__ float wrol[4 * 256];
    __shared__ float red[5 * 12 * 64];
    __shared__ float redB[16 * 64];
    __shared__ float hloc[4 * 64];
    __shared__ float bihl[12], bhhl[12], brol[4];
    const int d0 = (207 * wg) / NWG;
    const int d1 = (207 * (wg + 1)) / NWG;
    const int dc = d1 - d0;
    for (int i = tid; i < 12 * LDW; i += 256) {
        int r = i / LDW, c = i - r * LDW;
        int rg = (r >> 2) * 256 + wg * 4 + (r & 3);
        float v = 0.f;
        if (c < 414) v = W_ih[rg * 414 + c];
        else if (c >= 416 && c < 672) v = W_hh[rg * 256 + (c - 416)];
        wgl[i] = v;
    }
    for (int i = tid; i < 4 * 256; i += 256) {
        int dl_ = i >> 8, j = i & 255;
        wrol[i] = (dl_ < dc) ? W_ro[(d0 + dl_) * 256 + j] : 0.f;
    }
    if (tid < 12) {
        int rg = (tid >> 2) * 256 + wg * 4 + (tid & 3);
        bihl[tid] = b_ih[rg];
        bhhl[tid] = b_hh[rg];
    }
    if (tid < 4) brol[tid] = (tid < dc) ? b_ro[d0 + tid] : 0.f;
    hloc[tid] = 0.f;
    __syncthreads();
    const float4* A4 = (const float4*)actg;
    const int u = lane >> 4;
    const int bp = lane & 15;
    const bool have = (tid < dc * 64);
    const int dl = tid >> 6, b = tid & 63;
    const size_t gbase = (size_t)b * (SS * DD) + (d0 + dl);
    float xv_pf = 0.f, mv_pf = 0.f;
    if (have) { xv_pf = x[gbase]; mv_pf = mask[gbase]; }
    unsigned gen = 0;
    for (int t = 0; t < SS; ++t) {
        const int par = t & 1;
        const int hrow0 = V3_HBASE + par * 256;
        {
            const float* hrow = actg + hrow0 * 64;
            const int jb = wv * 64;
            float acc0 = 0.f, acc1 = 0.f, acc2 = 0.f, acc3 = 0.f;
            #pragma unroll 4
            for (int j = 0; j < 64; j += 4) {
                float a0 = hrow[(jb + j + 0) * 64 + lane];
                float a1 = hrow[(jb + j + 1) * 64 + lane];
                float a2 = hrow[(jb + j + 2) * 64 + lane];
                float a3 = hrow[(jb + j + 3) * 64 + lane];
                float4 w0 = *(const float4*)&wrol[0 * 256 + jb + j];
                float4 w1 = *(const float4*)&wrol[1 * 256 + jb + j];
                float4 w2 = *(const float4*)&wrol[2 * 256 + jb + j];
                float4 w3 = *(const float4*)&wrol[3 * 256 + jb + j];
                acc0 += a0*w0.x + a1*w0.y + a2*w0.z + a3*w0.w;
                acc1 += a0*w1.x + a1*w1.y + a2*w1.z + a3*w1.w;
                acc2 += a0*w2.x + a1*w2.y + a2*w2.z + a3*w2.w;
                acc3 += a0*w3.x + a1*w3.y + a2*w3.z + a3*w3.w;
            }
            redB[(wv * 4 + 0) * 64 + lane] = acc0;
            redB[(wv * 4 + 1) * 64 + lane] = acc1;
            redB[(wv * 4 + 2) * 64 + lane] = acc2;
            redB[(wv * 4 + 3) * 64 + lane] = acc3;
        }
        __syncthreads();
        if (have) {
            float xh = redB[(0 * 4 + dl) * 64 + b] + redB[(1 * 4 + dl) * 64 + b]
                     + redB[(2 * 4 + dl) * 64 + b] + redB[(3 * 4 + dl) * 64 + b]
                     + brol[dl];
            if (STAGE) stage[(t * DD + d0 + dl) * 64 + b] = xh;
            else       out[gbase + (size_t)t * DD] = xh;
            if (t < SS - 1) {
                float xi = (mv_pf > 0.5f) ? xv_pf : xh;
                actg[(d0 + dl) * 64 + b] = xi;
                actg[(207 + d0 + dl) * 64 + b] = mv_pf;
            }
        }
        if (t == SS - 1) break;
        if (have && t + 1 < SS - 1) {
            xv_pf = x[gbase + (size_t)(t + 1) * DD];
            mv_pf = mask[gbase + (size_t)(t + 1) * DD];
        }
        v3_gbar(flags, wg, ++gen);
        if (wv == 0)      run_range6(A4, wgl, red, u, bp, 0,   0,          168, 0);
        else if (wv == 1) run_range6(A4, wgl, red, u, bp, 168, 168,        168, 1);
        else if (wv == 2) {
            run_range6(A4, wgl, red, u, bp, 336, 336,        80,  2);
            run_range6(A4, wgl, red, u, bp, 416, hrow0,      96,  3);
        } else            run_range6(A4, wgl, red, u, bp, 512, hrow0 + 96, 160, 4);
        __syncthreads();
        {
            const int u2 = tid >> 6, b2 = tid & 63;
            float gir = red[(0*12 + 0 + u2)*64 + b2] + red[(1*12 + 0 + u2)*64 + b2]
                      + red[(2*12 + 0 + u2)*64 + b2] + bihl[0 + u2];
            float giz = red[(0*12 + 4 + u2)*64 + b2] + red[(1*12 + 4 + u2)*64 + b2]
                      + red[(2*12 + 4 + u2)*64 + b2] + bihl[4 + u2];
            float gin = red[(0*12 + 8 + u2)*64 + b2] + red[(1*12 + 8 + u2)*64 + b2]
                      + red[(2*12 + 8 + u2)*64 + b2] + bihl[8 + u2];
            float ghr = red[(3*12 + 0 + u2)*64 + b2] + red[(4*12 + 0 + u2)*64 + b2] + bhhl[0 + u2];
            float ghz = red[(3*12 + 4 + u2)*64 + b2] + red[(4*12 + 4 + u2)*64 + b2] + bhhl[4 + u2];
            float ghn = red[(3*12 + 8 + u2)*64 + b2] + red[(4*12 + 8 + u2)*64 + b2] + bhhl[8 + u2];
            float r = 1.f / (1.f + __expf(-(gir + ghr)));
            float z = 1.f / (1.f + __expf(-(giz + ghz)));
            float n = tanhf(gin + r * ghn);
            float hn = (1.f - z) * n + z * hloc[u2 * 64 + b2];
            hloc[u2 * 64 + b2] = hn;
            actg[(V3_HBASE + (par ^ 1) * 256 + wg * 4 + u2) * 64 + b2] = hn;
        }
        v3_gbar(flags, wg, ++gen);
    }
}

// ---- minimal fallback (one WG per batch) ----
__global__ __launch_bounds__(768) void rnn_fallback(
    const float* __restrict__ x, const float* __restrict__ mask,
    const float* __restrict__ W_ih, const float* __restrict__ W_hh,
    const float* __restrict__ b_ih, const float* __restrict__ b_hh,
    const float* __restrict__ W_ro, const float* __restrict__ b_ro,
    float* __restrict__ out)
{
    const int b = blockIdx.x, tid = threadIdx.x;
    __shared__ float h[HH];
    __shared__ float hnew[HH];
    __shared__ float xin[414 + 2];
    __shared__ float gi[768];
    __shared__ float gh[768];
    __shared__ float xhat[DD];
    const float bih = b_ih[tid], bhh = b_hh[tid];
    const float bro = (tid < DD) ? b_ro[tid] : 0.f;
    if (tid < HH) h[tid] = 0.f;
    if (tid < DD) xhat[tid] = bro;
    __syncthreads();
    const float* xb = x + (size_t)b * SS * DD;
    const float* mb = mask + (size_t)b * SS * DD;
    float* ob = out + (size_t)b * SS * DD;
    for (int t = 0; t < SS; ++t) {
        if (tid < DD) ob[t * DD + tid] = xhat[tid];
        if (t == SS - 1) break;
        if (tid < DD) {
            float m = mb[t * DD + tid], xv = xb[t * DD + tid];
            xin[tid] = (m > 0.5f) ? xv : xhat[tid];
            xin[DD + tid] = m;
        }
        __syncthreads();
        float accI = bih, accH = bhh;
        const float* wi = W_ih + (size_t)tid * 414;
        for (int k = 0; k < 414; ++k) accI += wi[k] * xin[k];
        const float* wh = W_hh + (size_t)tid * HH;
        for (int k = 0; k < HH; ++k) accH += wh[k] * h[k];
        gi[tid] = accI; gh[tid] = accH;
        __syncthreads();
        if (tid < HH) {
            float r = 1.f / (1.f + __expf(-(gi[tid] + gh[tid])));
            float z = 1.f / (1.f + __expf(-(gi[HH + tid] + gh[HH + tid])));
            float n = tanhf(gi[2 * HH + tid] + r * gh[2 * HH + tid]);
            hnew[tid] = (1.f - z) * n + z * h[tid];
        }
        __syncthreads();
        if (tid < DD) {
            float acc = bro;
            const float* wr = W_ro + (size_t)tid * HH;
            for (int k = 0; k < HH; ++k) acc += wr[k] * hnew[k];
            xhat[tid] = acc;
        }
        if (tid < HH) h[tid] = hnew[tid];
        __syncthreads();
    }
}

extern "C" void kernel_launch(void* const* d_in, const int* in_sizes, int n_in,
                              void* d_out, int out_size, void* d_ws, size_t ws_size,
                              hipStream_t stream) {
    const float* x    = (const float*)d_in[0];
    const float* mask = (const float*)d_in[1];
    const float* W_ih = (const float*)d_in[2];
    const float* W_hh = (const float*)d_in[3];
    const float* b_ih = (const float*)d_in[4];
    const float* b_hh = (const float*)d_in[5];
    const float* W_ro = (const float*)d_in[6];
    const float* b_ro = (const float*)d_in[7];
    float* out = (float*)d_out;
    float* ws  = (float*)d_ws;

    if (ws_size >= WS_NEED7) {
        hipLaunchKernelGGL(rnn_init7, dim3(64), dim3(256), 0, stream, ws);
        hipLaunchKernelGGL(rnn_persist7, dim3(GRID7), dim3(BS7), 0, stream,
                           x, mask, W_ih, W_hh, b_ih, b_hh, W_ro, b_ro, ws, out);
        hipLaunchKernelGGL(out_transpose, dim3(SS), dim3(256), 0, stream,
                           ws + BUF_FLOATS + FLAG_U32, out);
    } else if (ws_size >= V3_WS_FULL) {
        hipLaunchKernelGGL(v3_init, dim3(32), dim3(256), 0, stream, ws);
        hipLaunchKernelGGL((v3_persist<true>), dim3(NWG), dim3(256), 0, stream,
                           x, mask, W_ih, W_hh, b_ih, b_hh, W_ro, b_ro, ws, out);
        hipLaunchKernelGGL(out_transpose, dim3(SS), dim3(256), 0, stream,
                           ws + V3_ACT + V3_FLAGS, out);
    } else if (ws_size >= V3_WS_SMALL) {
        hipLaunchKernelGGL(v3_init, dim3(32), dim3(256), 0, stream, ws);
        hipLaunchKernelGGL((v3_persist<false>), dim3(NWG), dim3(256), 0, stream,
                           x, mask, W_ih, W_hh, b_ih, b_hh, W_ro, b_ro, ws, out);
    } else {
        hipLaunchKernelGGL(rnn_fallback, dim3(BB), dim3(768), 0, stream,
                           x, mask, W_ih, W_hh, b_ih, b_hh, W_ro, b_ro, out);
    }
}